// Round 6
// baseline (463.677 us; speedup 1.0000x reference)
//
#include <hip/hip_runtime.h>
#include <hip/hip_bf16.h>
#include <math.h>

// MessagePassingLayer on MI355X — round 15.
// r14 post-mortem: three different barrier-chained node structures all land
// at ~210us non-edge (floor ~45). Steady node counters (r13): VALU 9%,
// MFMA 6%, occ 33% -> latency-bound on the barrier-serialized phase chain.
// Fix: node_fused rebuilt BARRIER-FREE. One wave = one 16-row tile:
//  - feat loaded straight into MFMA A-fragments from global (no staging),
//  - 6 GEMM passes per wave against wave-private LDS slices (in-wave
//    ds ordering via lgkmcnt; zero __syncthreads),
//  - h kept in sW[w]; A1/P staged through sU[w]; coalesced 256B-run copies.
// Waves fully independent -> CU scheduler hides all latency across 16
// waves/CU. edge_fused / gemm_out / prep unchanged (one structural change
// per round).

typedef __bf16 bf16x8 __attribute__((ext_vector_type(8)));
typedef __bf16 bf16x2 __attribute__((ext_vector_type(2)));
typedef float floatx4 __attribute__((ext_vector_type(4)));
typedef unsigned int uintx4 __attribute__((ext_vector_type(4)));

#define LN_EPS 1e-5f

__device__ __forceinline__ unsigned short f2bf(float x) {
  unsigned int u = __float_as_uint(x);
  u = u + 0x7fffu + ((u >> 16) & 1u);
  return (unsigned short)(u >> 16);
}

// packed pair -> one v_cvt_pk_bf16_f32 (RNE): lo in [15:0], hi in [31:16]
__device__ __forceinline__ unsigned int pkbf(float lo, float hi) {
  bf16x2 v;
  v.x = (__bf16)lo;
  v.y = (__bf16)hi;
  return __builtin_bit_cast(unsigned int, v);
}

__device__ __forceinline__ unsigned short f2bfh(float x) {
  __bf16 h = (__bf16)x;
  return __builtin_bit_cast(unsigned short, h);
}

__device__ __forceinline__ float bf2f(unsigned short s) {
  return __uint_as_float(((unsigned int)s) << 16);
}

__device__ __forceinline__ float geluf(float x) {
  float t = x * x;
  float u = x * (2.3022080f + 0.1029434f * t);
  float e = __builtin_amdgcn_exp2f(-u);
  return x * __builtin_amdgcn_rcpf(1.0f + e);
}

__device__ __forceinline__ float sigmoidf_fast(float x) {
  float e = __builtin_amdgcn_exp2f(-1.44269504f * x);
  return __builtin_amdgcn_rcpf(1.0f + e);
}

// ---------------------------------------------------------------------------
// prep: 9 [128,128] fp32 weights -> bf16 [n][k] (transposed). 36 blocks.
// slots: 0 WsrcT 1 WdstT 2 W1aT 3 W1bT 4 W2T 5 W3T 6 Wg1aT 7 Wg1bT 8 WoutT
// ---------------------------------------------------------------------------
__global__ __launch_bounds__(256) void prep_weights(
    const float* w0, const float* w1, const float* w2, const float* w3,
    const float* w4, const float* w5, const float* w6, const float* w7,
    const float* w8, unsigned short* out) {
  const float* srcs[9] = {w0, w1, w2, w3, w4, w5, w6, w7, w8};
  int m = blockIdx.x >> 2, c = blockIdx.x & 3;
  const float* src = srcs[m] + c * 32 * 128;
  __shared__ unsigned short sT[128][35];
  int tid = threadIdx.x;

  for (int it = 0; it < 4; ++it) {
    int f4 = tid + it * 256;
    float4 v = ((const float4*)src)[f4];
    int krel = f4 >> 5;
    int n0 = (f4 & 31) * 4;
    sT[n0 + 0][krel] = f2bf(v.x);
    sT[n0 + 1][krel] = f2bf(v.y);
    sT[n0 + 2][krel] = f2bf(v.z);
    sT[n0 + 3][krel] = f2bf(v.w);
  }
  __syncthreads();
  unsigned short* dst = out + m * 16384 + c * 32;
  for (int it = 0; it < 2; ++it) {
    int ch = tid + it * 256;
    int n = ch >> 2, kc = (ch & 3) * 8;
    unsigned short tmp[8];
    for (int j = 0; j < 8; ++j) tmp[j] = sT[n][kc + j];
    *(int4*)(dst + n * 128 + kc) = *(const int4*)tmp;
  }
}

#define LDB(pB, B)                                              \
  do {                                                          \
    const unsigned short* _p = (pB);                            \
    for (int kb = 0; kb < 4; ++kb) {                            \
      B[0][kb] = *(const bf16x8*)(_p + kb * 32);                \
      B[1][kb] = *(const bf16x8*)(_p + 2048 + kb * 32);         \
    }                                                           \
  } while (0)

// ---------------------------------------------------------------------------
// node_fused (wave-independent, barrier-free): wave w owns rows
// [bid*64 + w*16, +16). Per wave:
//   fA = feat A-frags (direct global loads, fp32->bf16)
//   h_src = fA@Wsrc+b -> sW[w]; hA = A-frags from sW[w]
//   A1s = hA@W1a+b1 -> sU[w] -> copy SrcCat[:,0:128)
//   Ps  = hA@Wg1a+bg1 -> sU[w] -> copy SrcCat[:,128:256)
//   h_dst = fA@Wdst+b -> sW[w]; hA reload
//   A1d -> DstCat[:,0:128); Pd -> DstCat[:,128:256)
// Zero __syncthreads. LDS 2*17.4KB -> 4 blk/CU = 16 independent waves/CU.
// ---------------------------------------------------------------------------
__global__ __launch_bounds__(256, 4) void node_fused(
    const float* __restrict__ feat, const unsigned short* __restrict__ wT,
    const float* __restrict__ b_src, const float* __restrict__ b_dst,
    const float* __restrict__ b1, const float* __restrict__ bg1,
    unsigned short* __restrict__ SrcCat, unsigned short* __restrict__ DstCat,
    unsigned short* __restrict__ upd, int M) {
  __shared__ __align__(16) unsigned short sW[4][16][136];
  __shared__ __align__(16) unsigned short sU[4][16][136];
  int tid = threadIdx.x;
  int w = tid >> 6, lane = tid & 63, lr = lane & 15, q = lane >> 4;
  int r0 = blockIdx.x * 64 + w * 16;  // wave-private 16-row tile

  unsigned short (*mW)[136] = sW[w];
  unsigned short (*mU)[136] = sU[w];

  {  // zero upd rows [r0, r0+16): 16 rows x 16 int4
    int4 z = {0, 0, 0, 0};
#pragma unroll
    for (int j = 0; j < 4; ++j) {
      int idx = lane + j * 64;
      int row = idx >> 4, c = idx & 15;
      if (r0 + row < M)
        ((int4*)(upd + (long long)(r0 + row) * 128))[c] = z;
    }
  }

  // feat A-frags: lane (lr,q) holds feat[r0+lr][q*8 + kb*32 .. +8]
  bf16x8 fA[4];
  {
    int frow = r0 + lr;
    bool fok = frow < M;
    const float* fp = feat + (long long)frow * 128 + q * 8;
#pragma unroll
    for (int kb = 0; kb < 4; ++kb) {
      float4 a = {0.f, 0.f, 0.f, 0.f}, b = {0.f, 0.f, 0.f, 0.f};
      if (fok) {
        a = *(const float4*)(fp + kb * 32);
        b = *(const float4*)(fp + kb * 32 + 4);
      }
      uintx4 u;
      u.x = pkbf(a.x, a.y);
      u.y = pkbf(a.z, a.w);
      u.z = pkbf(b.x, b.y);
      u.w = pkbf(b.z, b.w);
      fA[kb] = __builtin_bit_cast(bf16x8, u);
    }
  }

  floatx4 acc[8];
  bf16x8 hA[4];

  auto zacc = [&]() {
#pragma unroll
    for (int nt = 0; nt < 8; ++nt) acc[nt] = (floatx4){0.f, 0.f, 0.f, 0.f};
  };
  // one full GEMM pass: acc[nt] = Af @ W(slot), output cols nt*16+lr
  auto gemm = [&](const unsigned short* wbase, const bf16x8 (&Af)[4]) {
#pragma unroll
    for (int nt = 0; nt < 8; ++nt) {
      const unsigned short* bp = wbase + (nt * 16 + lr) * 128 + q * 8;
      bf16x8 B0 = *(const bf16x8*)(bp);
      bf16x8 B1 = *(const bf16x8*)(bp + 32);
      bf16x8 B2 = *(const bf16x8*)(bp + 64);
      bf16x8 B3 = *(const bf16x8*)(bp + 96);
      acc[nt] = __builtin_amdgcn_mfma_f32_16x16x32_bf16(Af[0], B0, acc[nt], 0, 0, 0);
      acc[nt] = __builtin_amdgcn_mfma_f32_16x16x32_bf16(Af[1], B1, acc[nt], 0, 0, 0);
      acc[nt] = __builtin_amdgcn_mfma_f32_16x16x32_bf16(Af[2], B2, acc[nt], 0, 0, 0);
      acc[nt] = __builtin_amdgcn_mfma_f32_16x16x32_bf16(Af[3], B3, acc[nt], 0, 0, 0);
    }
  };
  // stage C-frags (+bias) into LDS slice as bf16
  auto stage = [&](unsigned short (*S)[136], const float* bias) {
#pragma unroll
    for (int nt = 0; nt < 8; ++nt) {
      float bv = bias ? bias[nt * 16 + lr] : 0.f;
#pragma unroll
      for (int i = 0; i < 4; ++i)
        S[4 * q + i][nt * 16 + lr] = f2bfh(acc[nt][i] + bv);
    }
  };
  // A-frags from LDS slice: lane (lr,q) reads S[lr][q*8 + kb*32 .. +8]
  auto loadA = [&](unsigned short (*S)[136]) {
#pragma unroll
    for (int kb = 0; kb < 4; ++kb)
      hA[kb] = *(const bf16x8*)&S[lr][kb * 32 + q * 8];
  };
  // coalesced copy of 16x128 bf16 slice into Cat cols [base, base+128)
  auto copy16 = [&](unsigned short* dstbase, const unsigned short (*S)[136]) {
#pragma unroll
    for (int j = 0; j < 4; ++j) {
      int idx = lane + j * 64;
      int row = idx >> 4, c = idx & 15;
      if (r0 + row < M)
        *(int4*)(dstbase + (long long)(r0 + row) * 256 + c * 8) =
            *(const int4*)&S[row][c * 8];
    }
  };

  // ---- SRC half ----
  zacc();
  gemm(wT + 0 * 16384, fA);      // h_src
  stage(mW, b_src);
  loadA(mW);
  zacc();
  gemm(wT + 2 * 16384, hA);      // A1s
  stage(mU, b1);
  copy16(SrcCat, mU);
  zacc();
  gemm(wT + 6 * 16384, hA);      // Ps
  stage(mU, bg1);
  copy16(SrcCat + 128, mU);

  // ---- DST half ----
  zacc();
  gemm(wT + 1 * 16384, fA);      // h_dst
  stage(mW, b_dst);
  loadA(mW);
  zacc();
  gemm(wT + 3 * 16384, hA);      // A1d
  stage(mU, nullptr);
  copy16(DstCat, mU);
  zacc();
  gemm(wT + 7 * 16384, hA);      // Pd
  stage(mU, nullptr);
  copy16(DstCat + 128, mU);
}

// ---------------------------------------------------------------------------
// out GEMM (r10 64-row version): d_out = upd(bf16)@Wout + b_out (fp32 out)
// ---------------------------------------------------------------------------
__global__ __launch_bounds__(256, 4) void gemm_out(
    const unsigned short* __restrict__ A, const unsigned short* __restrict__ Bt,
    const float* __restrict__ bias, float* __restrict__ C, int M) {
  __shared__ __align__(16) char smem[64 * 130 * 4];  // 33280 B
  unsigned short (*sA)[136] = (unsigned short(*)[136])smem;   // staging (17 KB)
  float (*sO)[130] = (float(*)[130])smem;                     // fp32 out tile
  int tid = threadIdx.x;
  int r0 = blockIdx.x * 64;

  {
    int r = tid >> 2, seg = tid & 3;
    int row = r0 + r;
    const int4* src = (const int4*)(A + (long long)row * 128);
    for (int it = 0; it < 4; ++it) {
      int c = seg * 4 + it;
      int4 v;
      if (row < M) v = src[c];
      else v = (int4){0, 0, 0, 0};
      *(int4*)&sA[r][c * 8] = v;
    }
  }
  __syncthreads();

  int w = tid >> 6, lane = tid & 63, lr = lane & 15, q = lane >> 4;
  int c0 = 32 * w + lr, c1 = 32 * w + 16 + lr;
  const unsigned short* pB = Bt + c0 * 128 + q * 8;

  bf16x8 B[2][4];
  LDB(pB, B);
  floatx4 acc[4][2];
  for (int mb = 0; mb < 4; ++mb)
    for (int nb = 0; nb < 2; ++nb) acc[mb][nb] = (floatx4){0.f, 0.f, 0.f, 0.f};
  for (int kb = 0; kb < 4; ++kb) {
    int k = kb * 32 + q * 8;
    for (int mb = 0; mb < 4; ++mb) {
      bf16x8 a = *(const bf16x8*)&sA[16 * mb + lr][k];
      acc[mb][0] = __builtin_amdgcn_mfma_f32_16x16x32_bf16(a, B[0][kb], acc[mb][0], 0, 0, 0);
      acc[mb][1] = __builtin_amdgcn_mfma_f32_16x16x32_bf16(a, B[1][kb], acc[mb][1], 0, 0, 0);
    }
  }
  __syncthreads();  // all sA reads done before fp32 overwrite

  float bv0 = bias[c0], bv1 = bias[c1];
  for (int mb = 0; mb < 4; ++mb)
    for (int i = 0; i < 4; ++i) {
      int r = 16 * mb + 4 * q + i;
      sO[r][c0] = acc[mb][0][i] + bv0;
      sO[r][c1] = acc[mb][1][i] + bv1;
    }
  __syncthreads();  // fp32 tile visible

  for (int it = 0; it < 8; ++it) {
    int idx = tid + it * 256;
    int row = idx >> 5, c = idx & 31;
    if (r0 + row < M)
      *(float4*)(C + (long long)(r0 + row) * 128 + c * 4) = *(const float4*)&sO[row][c * 4];
  }
}

// ---------------------------------------------------------------------------
// edge_fused: 64 edges/block, 256 thr (r12 body, unchanged; single dispatch).
// ---------------------------------------------------------------------------
__global__ __launch_bounds__(256, 6) void edge_fused(
    const unsigned short* __restrict__ SrcCat, const unsigned short* __restrict__ DstCat,
    const int* __restrict__ edge_src, const int* __restrict__ edge_dst,
    const unsigned short* __restrict__ wT,
    const float* __restrict__ b2, const float* __restrict__ b3,
    const float* __restrict__ ln_g, const float* __restrict__ ln_b,
    const float* __restrict__ Wg2, const float* __restrict__ bg2,
    unsigned short* __restrict__ upd, int E) {
  __shared__ __align__(16) unsigned short sH[64][136];  // h1 then h2 (in place)
  __shared__ int sDst[64];
  __shared__ float sGate[64];
  __shared__ float sR1[4][64];
  __shared__ float sR2[4][64];
  __shared__ float sM[64];
  __shared__ float sRS[64];
  // total: 17408 + 256 + 256 + 1024 + 1024 + 256 + 256 = 20480 B

  int tid = threadIdx.x;
  int e0 = blockIdx.x * 64;

  {  // gather + h1 + gate (partials reduced in-wave: seg quad = adjacent lanes)
    int r = tid >> 2, seg = tid & 3;
    int e = e0 + r;
    int ee = (e < E) ? e : (E - 1);
    int es = edge_src[ee], ed = edge_dst[ee];
    if (seg == 0) sDst[r] = (e < E) ? ed : -1;
    const unsigned short* ps = SrcCat + (long long)es * 256 + seg * 32;
    const unsigned short* pd = DstCat + (long long)ed * 256 + seg * 32;

    int4 sa[4], sb[4], ga[4], gb[4];
    for (int u = 0; u < 4; ++u) {
      sa[u] = ((const int4*)ps)[u];
      sb[u] = ((const int4*)pd)[u];
      ga[u] = ((const int4*)(ps + 128))[u];
      gb[u] = ((const int4*)(pd + 128))[u];
    }
    for (int u = 0; u < 4; ++u) {
      const unsigned short* av = (const unsigned short*)&sa[u];
      const unsigned short* bv = (const unsigned short*)&sb[u];
      unsigned int ov[4];
      for (int j = 0; j < 4; ++j) {
        float g0 = geluf(bf2f(av[2 * j])     + bf2f(bv[2 * j]));
        float g1 = geluf(bf2f(av[2 * j + 1]) + bf2f(bv[2 * j + 1]));
        ov[j] = pkbf(g0, g1);
      }
      *(int4*)&sH[r][seg * 32 + u * 8] = *(const int4*)ov;
    }
    float gp = 0.f;
    for (int u = 0; u < 4; ++u) {
      const unsigned short* av = (const unsigned short*)&ga[u];
      const unsigned short* bv = (const unsigned short*)&gb[u];
      float4 w0 = *(const float4*)(Wg2 + seg * 32 + u * 8);
      float4 w1 = *(const float4*)(Wg2 + seg * 32 + u * 8 + 4);
      gp += geluf(bf2f(av[0]) + bf2f(bv[0])) * w0.x;
      gp += geluf(bf2f(av[1]) + bf2f(bv[1])) * w0.y;
      gp += geluf(bf2f(av[2]) + bf2f(bv[2])) * w0.z;
      gp += geluf(bf2f(av[3]) + bf2f(bv[3])) * w0.w;
      gp += geluf(bf2f(av[4]) + bf2f(bv[4])) * w1.x;
      gp += geluf(bf2f(av[5]) + bf2f(bv[5])) * w1.y;
      gp += geluf(bf2f(av[6]) + bf2f(bv[6])) * w1.z;
      gp += geluf(bf2f(av[7]) + bf2f(bv[7])) * w1.w;
    }
    gp += __shfl_xor(gp, 1);
    gp += __shfl_xor(gp, 2);
    if (seg == 0) sGate[r] = sigmoidf_fast(gp + bg2[0]);
  }
  __syncthreads();  // B1: h1 + gate + dst staged

  int w = tid >> 6, lane = tid & 63, lr = lane & 15, q = lane >> 4;
  int c0 = 32 * w + lr, c1 = 32 * w + 16 + lr;
  const unsigned short* pB = wT + c0 * 128 + q * 8;

  bf16x8 B[2][4];
  floatx4 acc[4][2];
  auto zacc = [&]() {
    for (int mb = 0; mb < 4; ++mb)
      for (int nb = 0; nb < 2; ++nb) acc[mb][nb] = (floatx4){0.f, 0.f, 0.f, 0.f};
  };
  auto pass = [&](const unsigned short (*Ab)[136]) {
    for (int kb = 0; kb < 4; ++kb) {
      int k = kb * 32 + q * 8;
      for (int mb = 0; mb < 4; ++mb) {
        bf16x8 a = *(const bf16x8*)&Ab[16 * mb + lr][k];
        acc[mb][0] = __builtin_amdgcn_mfma_f32_16x16x32_bf16(a, B[0][kb], acc[mb][0], 0, 0, 0);
        acc[mb][1] = __builtin_amdgcn_mfma_f32_16x16x32_bf16(a, B[1][kb], acc[mb][1], 0, 0, 0);
      }
    }
  };

  // ---- stage 2: h2 = gelu(h1@W2 + b2), written back into sH in place ----
  LDB(pB + 4 * 16384, B);
  zacc();
  pass(sH);
  __syncthreads();  // B2: all h1 reads drained before overwrite
  {
    float bv0 = b2[c0], bv1 = b2[c1];
    for (int mb = 0; mb < 4; ++mb)
      for (int i = 0; i < 4; ++i) {
        int r = 16 * mb + 4 * q + i;
        unsigned int u = pkbf(geluf(acc[mb][0][i] + bv0), geluf(acc[mb][1][i] + bv1));
        sH[r][c0] = (unsigned short)u;
        sH[r][c1] = (unsigned short)(u >> 16);
      }
  }
  __syncthreads();  // B3: h2 tile visible

  // ---- stage 3 + LN partials ----
  LDB(pB + 5 * 16384, B);
  zacc();
  pass(sH);
  {
    float bv0 = b3[c0], bv1 = b3[c1];
    for (int mb = 0; mb < 4; ++mb)
      for (int i = 0; i < 4; ++i) {
        float x0 = acc[mb][0][i] + bv0;
        float x1 = acc[mb][1][i] + bv1;
        acc[mb][0][i] = x0; acc[mb][1][i] = x1;
        float s = x0 + x1, s2 = x0 * x0 + x1 * x1;
        s += __shfl_xor(s, 1); s += __shfl_xor(s, 2);
        s += __shfl_xor(s, 4); s += __shfl_xor(s, 8);
        s2 += __shfl_xor(s2, 1); s2 += __shfl_xor(s2, 2);
        s2 += __shfl_xor(s2, 4); s2 += __shfl_xor(s2, 8);
        if (lr == 0) { sR1[w][16 * mb + 4 * q + i] = s; sR2[w][16 * mb + 4 * q + i] = s2; }
      }
  }
  __syncthreads();  // B4
  if (tid < 64) {
    float s = sR1[0][tid] + sR1[1][tid] + sR1[2][tid] + sR1[3][tid];
    float s2 = sR2[0][tid] + sR2[1][tid] + sR2[2][tid] + sR2[3][tid];
    float m = s * (1.f / 128.f);
    float v = s2 * (1.f / 128.f) - m * m;
    sM[tid] = m;
    sRS[tid] = rsqrtf(v + LN_EPS);
  }
  __syncthreads();  // B5

  {
    float lg0 = ln_g[c0], lg1 = ln_g[c1];
    float lb0 = ln_b[c0], lb1 = ln_b[c1];
    for (int mb = 0; mb < 4; ++mb)
      for (int i = 0; i < 4; ++i) {
        int r = 16 * mb + 4 * q + i;
        int dst = sDst[r];
        float m = sM[r], rs = sRS[r], gt = sGate[r];
        float v0 = ((acc[mb][0][i] - m) * rs * lg0 + lb0) * gt;
        float v1 = ((acc[mb][1][i] - m) * rs * lg1 + lb1) * gt;
        float o0 = __shfl_xor(v0, 1);
        float o1 = __shfl_xor(v1, 1);
        if (dst >= 0) {
          unsigned int pk;
          int colb;
          if ((lr & 1) == 0) {
            pk = pkbf(v0, o0);
            colb = c0;
          } else {
            pk = pkbf(o1, v1);
            colb = c0 + 15;
          }
          unsigned short* addr = upd + (long long)dst * 128 + colb;
          asm volatile("global_atomic_pk_add_bf16 %0, %1, off"
                       :: "v"(addr), "v"(pk) : "memory");
        }
      }
  }
}

// ---------------------------------------------------------------------------
extern "C" void kernel_launch(void* const* d_in, const int* in_sizes, int n_in,
                              void* d_out, int out_size, void* d_ws, size_t ws_size,
                              hipStream_t stream) {
  const float* feat   = (const float*)d_in[0];
  const int* edge_src = (const int*)d_in[1];
  const int* edge_dst = (const int*)d_in[2];
  const float* W_src = (const float*)d_in[3];  const float* b_src = (const float*)d_in[4];
  const float* W_dst = (const float*)d_in[5];  const float* b_dst = (const float*)d_in[6];
  const float* W1a = (const float*)d_in[7];    const float* W1b = (const float*)d_in[8];
  const float* b1  = (const float*)d_in[9];
  const float* W2  = (const float*)d_in[10];   const float* b2  = (const float*)d_in[11];
  const float* W3  = (const float*)d_in[12];   const float* b3  = (const float*)d_in[13];
  const float* ln_g = (const float*)d_in[14];  const float* ln_b = (const float*)d_in[15];
  const float* Wg1a = (const float*)d_in[16];  const float* Wg1b = (const float*)d_in[17];
  const float* bg1  = (const float*)d_in[18];
  const float* Wg2  = (const float*)d_in[19];  const float* bg2 = (const float*)d_in[20];
  const float* W_out = (const float*)d_in[21]; const float* b_out = (const float*)d_in[22];

  int N = in_sizes[0] / 128;   // 100000
  int E = in_sizes[1];         // 400000

  // ws: [wT 288KB][SrcCat bf16 N*256][DstCat bf16 N*256][upd bf16 N*128]
  char* ws = (char*)d_ws;
  unsigned short* wT = (unsigned short*)ws;
  size_t off = 9 * 16384 * sizeof(unsigned short);
  unsigned short* SrcCat = (unsigned short*)(ws + off);
  off += (size_t)N * 256 * sizeof(unsigned short);
  unsigned short* DstCat = (unsigned short*)(ws + off);
  off += (size_t)N * 256 * sizeof(unsigned short);
  unsigned short* upd = (unsigned short*)(ws + off);

  prep_weights<<<36, 256, 0, stream>>>(W_src, W_dst, W1a, W1b, W2, W3, Wg1a, Wg1b,
                                       W_out, wT);
  int mtiles = (N + 63) / 64;
  node_fused<<<mtiles, 256, 0, stream>>>(feat, wT, b_src, b_dst, b1, bg1,
                                         SrcCat, DstCat, upd, N);
  edge_fused<<<(E + 63) / 64, 256, 0, stream>>>(SrcCat, DstCat, edge_src, edge_dst,
                                                wT, b2, b3, ln_g, ln_b, Wg2, bg2,
                                                upd, E);
  gemm_out<<<mtiles, 256, 0, stream>>>(upd, wT + 8 * 16384, b_out, (float*)d_out, N);
}

// Round 7
// 373.694 us; speedup vs baseline: 1.2408x; 1.2408x over previous
//
#include <hip/hip_runtime.h>
#include <hip/hip_bf16.h>
#include <math.h>

// MessagePassingLayer on MI355X — round 16: best-of-breed consolidation.
// r15 post-mortem: barrier-free node streamed B from global per-MFMA with
// 64 VGPR -> latency-serialized (182us, all pipes idle). r13/r14 structures
// also lost to r10. Edge variance across containers is +-13% on identical
// code, which contaminated earlier comparisons.
// This round: r10's proven node_fused/gemm_out (64-row, y-split, B-in-reg,
// LDS-staged coalesced epilogue) + pkbf conversions (r12-proven, identical
// RNE rounding) + r12's edge_fused (pkbf, best measured 158us). Establishes
// the portfolio-best configuration as one kernel.

typedef __bf16 bf16x8 __attribute__((ext_vector_type(8)));
typedef __bf16 bf16x2 __attribute__((ext_vector_type(2)));
typedef float floatx4 __attribute__((ext_vector_type(4)));

#define LN_EPS 1e-5f

__device__ __forceinline__ unsigned short f2bf(float x) {
  unsigned int u = __float_as_uint(x);
  u = u + 0x7fffu + ((u >> 16) & 1u);
  return (unsigned short)(u >> 16);
}

// packed pair -> one v_cvt_pk_bf16_f32 (RNE): lo in [15:0], hi in [31:16]
__device__ __forceinline__ unsigned int pkbf(float lo, float hi) {
  bf16x2 v;
  v.x = (__bf16)lo;
  v.y = (__bf16)hi;
  return __builtin_bit_cast(unsigned int, v);
}

__device__ __forceinline__ float bf2f(unsigned short s) {
  return __uint_as_float(((unsigned int)s) << 16);
}

__device__ __forceinline__ float geluf(float x) {
  float t = x * x;
  float u = x * (2.3022080f + 0.1029434f * t);
  float e = __builtin_amdgcn_exp2f(-u);
  return x * __builtin_amdgcn_rcpf(1.0f + e);
}

__device__ __forceinline__ float sigmoidf_fast(float x) {
  float e = __builtin_amdgcn_exp2f(-1.44269504f * x);
  return __builtin_amdgcn_rcpf(1.0f + e);
}

// ---------------------------------------------------------------------------
// prep: 9 [128,128] fp32 weights -> bf16 [n][k] (transposed). 36 blocks.
// slots: 0 WsrcT 1 WdstT 2 W1aT 3 W1bT 4 W2T 5 W3T 6 Wg1aT 7 Wg1bT 8 WoutT
// ---------------------------------------------------------------------------
__global__ __launch_bounds__(256) void prep_weights(
    const float* w0, const float* w1, const float* w2, const float* w3,
    const float* w4, const float* w5, const float* w6, const float* w7,
    const float* w8, unsigned short* out) {
  const float* srcs[9] = {w0, w1, w2, w3, w4, w5, w6, w7, w8};
  int m = blockIdx.x >> 2, c = blockIdx.x & 3;
  const float* src = srcs[m] + c * 32 * 128;
  __shared__ unsigned short sT[128][35];
  int tid = threadIdx.x;

  for (int it = 0; it < 4; ++it) {
    int f4 = tid + it * 256;
    float4 v = ((const float4*)src)[f4];
    int krel = f4 >> 5;
    int n0 = (f4 & 31) * 4;
    sT[n0 + 0][krel] = f2bf(v.x);
    sT[n0 + 1][krel] = f2bf(v.y);
    sT[n0 + 2][krel] = f2bf(v.z);
    sT[n0 + 3][krel] = f2bf(v.w);
  }
  __syncthreads();
  unsigned short* dst = out + m * 16384 + c * 32;
  for (int it = 0; it < 2; ++it) {
    int ch = tid + it * 256;
    int n = ch >> 2, kc = (ch & 3) * 8;
    unsigned short tmp[8];
    for (int j = 0; j < 8; ++j) tmp[j] = sT[n][kc + j];
    *(int4*)(dst + n * 128 + kc) = *(const int4*)tmp;
  }
}

#define LDB(pB, B)                                              \
  do {                                                          \
    const unsigned short* _p = (pB);                            \
    for (int kb = 0; kb < 4; ++kb) {                            \
      B[0][kb] = *(const bf16x8*)(_p + kb * 32);                \
      B[1][kb] = *(const bf16x8*)(_p + 2048 + kb * 32);         \
    }                                                           \
  } while (0)

// ---------------------------------------------------------------------------
// node_fused (r10 structure): blockIdx.y=0 -> SrcCat, y=1 -> DstCat.
// y==0 blocks also zero their 64 rows of upd (bf16).
// B in registers per pass (8 loads), A streamed from LDS, outputs staged
// through sF/sT then one coalesced int4 copy phase. pkbf conversions.
// ---------------------------------------------------------------------------
__global__ __launch_bounds__(256, 4) void node_fused(
    const float* __restrict__ feat, const unsigned short* __restrict__ wT,
    const float* __restrict__ b_src, const float* __restrict__ b_dst,
    const float* __restrict__ b1, const float* __restrict__ bg1,
    unsigned short* __restrict__ SrcCat, unsigned short* __restrict__ DstCat,
    unsigned short* __restrict__ upd, int M) {
  __shared__ __align__(16) unsigned short sF[64][136];
  __shared__ __align__(16) unsigned short sT[64][136];
  int tid = threadIdx.x;
  int r0 = blockIdx.x * 64;
  int y = blockIdx.y;

  if (y == 0) {  // zero upd rows [r0, r0+64): 1024 int4
    int4 z = {0, 0, 0, 0};
    int4* p = (int4*)(upd + (long long)r0 * 128);
    for (int it = 0; it < 4; ++it) {
      int idx = tid + it * 256;
      if (r0 + (idx >> 4) < M) p[idx] = z;
    }
  }

  {  // stage feat -> sF (pkbf packed)
    int r = tid >> 2, seg = tid & 3;
    int row = r0 + r;
    const float* src = feat + (long long)row * 128 + seg * 32;
    for (int j = 0; j < 4; ++j) {
      unsigned int tmp[4];
      if (row < M) {
        float4 f0 = *(const float4*)(src + j * 8);
        float4 f1 = *(const float4*)(src + j * 8 + 4);
        tmp[0] = pkbf(f0.x, f0.y);
        tmp[1] = pkbf(f0.z, f0.w);
        tmp[2] = pkbf(f1.x, f1.y);
        tmp[3] = pkbf(f1.z, f1.w);
      } else {
        tmp[0] = tmp[1] = tmp[2] = tmp[3] = 0;
      }
      *(int4*)&sF[r][seg * 32 + j * 8] = *(const int4*)tmp;
    }
  }
  __syncthreads();  // B1: feat staged

  int w = tid >> 6, lane = tid & 63, lr = lane & 15, q = lane >> 4;
  int c0 = 32 * w + lr, c1 = c0 + 16;
  const unsigned short* pB = wT + c0 * 128 + q * 8;

  const unsigned short* wH = pB + (y ? 1 : 0) * 16384;
  const unsigned short* wA = pB + (y ? 3 : 2) * 16384;
  const unsigned short* wG = pB + (y ? 7 : 6) * 16384;
  unsigned short* Cat = y ? DstCat : SrcCat;
  float hb0 = y ? b_dst[c0] : b_src[c0];
  float hb1 = y ? b_dst[c1] : b_src[c1];
  float ab0 = y ? 0.f : b1[c0];
  float ab1 = y ? 0.f : b1[c1];
  float gb0 = y ? 0.f : bg1[c0];
  float gb1 = y ? 0.f : bg1[c1];

  bf16x8 B[2][4];

  auto pass = [&](const unsigned short (*Ab)[136], floatx4 (&acc)[4][2]) {
    for (int kb = 0; kb < 4; ++kb) {
      int k = kb * 32 + q * 8;
      for (int mb = 0; mb < 4; ++mb) {
        bf16x8 a = *(const bf16x8*)&Ab[16 * mb + lr][k];
        acc[mb][0] = __builtin_amdgcn_mfma_f32_16x16x32_bf16(a, B[0][kb], acc[mb][0], 0, 0, 0);
        acc[mb][1] = __builtin_amdgcn_mfma_f32_16x16x32_bf16(a, B[1][kb], acc[mb][1], 0, 0, 0);
      }
    }
  };

  // h = feat@W{src,dst} + b -> sT
  {
    floatx4 acc[4][2];
    for (int mb = 0; mb < 4; ++mb)
      for (int nb = 0; nb < 2; ++nb) acc[mb][nb] = (floatx4){0.f, 0.f, 0.f, 0.f};
    LDB(wH, B);
    pass(sF, acc);
    for (int mb = 0; mb < 4; ++mb)
      for (int i = 0; i < 4; ++i) {
        int r = 16 * mb + 4 * q + i;
        unsigned int u = pkbf(acc[mb][0][i] + hb0, acc[mb][1][i] + hb1);
        sT[r][c0] = (unsigned short)u;
        sT[r][c1] = (unsigned short)(u >> 16);
      }
  }
  __syncthreads();  // B2: h tile visible; all sF reads done

  floatx4 accA[4][2], accP[4][2];
  for (int mb = 0; mb < 4; ++mb)
    for (int nb = 0; nb < 2; ++nb) {
      accA[mb][nb] = (floatx4){0.f, 0.f, 0.f, 0.f};
      accP[mb][nb] = (floatx4){0.f, 0.f, 0.f, 0.f};
    }
  LDB(wA, B);
  pass(sT, accA);
  LDB(wG, B);
  pass(sT, accP);
  __syncthreads();  // B3: all sT reads done

  // A1 -> sF, P -> sT (overwrite)
  for (int mb = 0; mb < 4; ++mb)
    for (int i = 0; i < 4; ++i) {
      int r = 16 * mb + 4 * q + i;
      unsigned int ua = pkbf(accA[mb][0][i] + ab0, accA[mb][1][i] + ab1);
      sF[r][c0] = (unsigned short)ua;
      sF[r][c1] = (unsigned short)(ua >> 16);
      unsigned int up = pkbf(accP[mb][0][i] + gb0, accP[mb][1][i] + gb1);
      sT[r][c0] = (unsigned short)up;
      sT[r][c1] = (unsigned short)(up >> 16);
    }
  __syncthreads();  // B4: staged output visible

  // coalesced copy: 64 rows x 256 cols bf16 = 2048 int4, 8 per thread
  for (int it = 0; it < 8; ++it) {
    int idx = tid + it * 256;
    int row = idx >> 5, c = idx & 31;   // c in [0,32): col chunk of 8
    if (r0 + row < M) {
      const void* src = (c < 16) ? (const void*)&sF[row][c * 8]
                                 : (const void*)&sT[row][(c - 16) * 8];
      *(int4*)(Cat + (long long)(r0 + row) * 256 + c * 8) = *(const int4*)src;
    }
  }
}

// ---------------------------------------------------------------------------
// out GEMM (r10 64-row version): d_out = upd(bf16)@Wout + b_out (fp32 out)
// ---------------------------------------------------------------------------
__global__ __launch_bounds__(256, 4) void gemm_out(
    const unsigned short* __restrict__ A, const unsigned short* __restrict__ Bt,
    const float* __restrict__ bias, float* __restrict__ C, int M) {
  __shared__ __align__(16) char smem[64 * 130 * 4];  // 33280 B
  unsigned short (*sA)[136] = (unsigned short(*)[136])smem;   // staging (17 KB)
  float (*sO)[130] = (float(*)[130])smem;                     // fp32 out tile
  int tid = threadIdx.x;
  int r0 = blockIdx.x * 64;

  {
    int r = tid >> 2, seg = tid & 3;
    int row = r0 + r;
    const int4* src = (const int4*)(A + (long long)row * 128);
    for (int it = 0; it < 4; ++it) {
      int c = seg * 4 + it;
      int4 v;
      if (row < M) v = src[c];
      else v = (int4){0, 0, 0, 0};
      *(int4*)&sA[r][c * 8] = v;
    }
  }
  __syncthreads();

  int w = tid >> 6, lane = tid & 63, lr = lane & 15, q = lane >> 4;
  int c0 = 32 * w + lr, c1 = 32 * w + 16 + lr;
  const unsigned short* pB = Bt + c0 * 128 + q * 8;

  bf16x8 B[2][4];
  LDB(pB, B);
  floatx4 acc[4][2];
  for (int mb = 0; mb < 4; ++mb)
    for (int nb = 0; nb < 2; ++nb) acc[mb][nb] = (floatx4){0.f, 0.f, 0.f, 0.f};
  for (int kb = 0; kb < 4; ++kb) {
    int k = kb * 32 + q * 8;
    for (int mb = 0; mb < 4; ++mb) {
      bf16x8 a = *(const bf16x8*)&sA[16 * mb + lr][k];
      acc[mb][0] = __builtin_amdgcn_mfma_f32_16x16x32_bf16(a, B[0][kb], acc[mb][0], 0, 0, 0);
      acc[mb][1] = __builtin_amdgcn_mfma_f32_16x16x32_bf16(a, B[1][kb], acc[mb][1], 0, 0, 0);
    }
  }
  __syncthreads();  // all sA reads done before fp32 overwrite

  float bv0 = bias[c0], bv1 = bias[c1];
  for (int mb = 0; mb < 4; ++mb)
    for (int i = 0; i < 4; ++i) {
      int r = 16 * mb + 4 * q + i;
      sO[r][c0] = acc[mb][0][i] + bv0;
      sO[r][c1] = acc[mb][1][i] + bv1;
    }
  __syncthreads();  // fp32 tile visible

  for (int it = 0; it < 8; ++it) {
    int idx = tid + it * 256;
    int row = idx >> 5, c = idx & 31;
    if (r0 + row < M)
      *(float4*)(C + (long long)(r0 + row) * 128 + c * 4) = *(const float4*)&sO[row][c * 4];
  }
}

// ---------------------------------------------------------------------------
// edge_fused: 64 edges/block, 256 thr (r12 body, unchanged; single dispatch).
// ---------------------------------------------------------------------------
__global__ __launch_bounds__(256, 6) void edge_fused(
    const unsigned short* __restrict__ SrcCat, const unsigned short* __restrict__ DstCat,
    const int* __restrict__ edge_src, const int* __restrict__ edge_dst,
    const unsigned short* __restrict__ wT,
    const float* __restrict__ b2, const float* __restrict__ b3,
    const float* __restrict__ ln_g, const float* __restrict__ ln_b,
    const float* __restrict__ Wg2, const float* __restrict__ bg2,
    unsigned short* __restrict__ upd, int E) {
  __shared__ __align__(16) unsigned short sH[64][136];  // h1 then h2 (in place)
  __shared__ int sDst[64];
  __shared__ float sGate[64];
  __shared__ float sR1[4][64];
  __shared__ float sR2[4][64];
  __shared__ float sM[64];
  __shared__ float sRS[64];
  // total: 17408 + 256 + 256 + 1024 + 1024 + 256 + 256 = 20480 B

  int tid = threadIdx.x;
  int e0 = blockIdx.x * 64;

  {  // gather + h1 + gate (partials reduced in-wave: seg quad = adjacent lanes)
    int r = tid >> 2, seg = tid & 3;
    int e = e0 + r;
    int ee = (e < E) ? e : (E - 1);
    int es = edge_src[ee], ed = edge_dst[ee];
    if (seg == 0) sDst[r] = (e < E) ? ed : -1;
    const unsigned short* ps = SrcCat + (long long)es * 256 + seg * 32;
    const unsigned short* pd = DstCat + (long long)ed * 256 + seg * 32;

    int4 sa[4], sb[4], ga[4], gb[4];
    for (int u = 0; u < 4; ++u) {
      sa[u] = ((const int4*)ps)[u];
      sb[u] = ((const int4*)pd)[u];
      ga[u] = ((const int4*)(ps + 128))[u];
      gb[u] = ((const int4*)(pd + 128))[u];
    }
    for (int u = 0; u < 4; ++u) {
      const unsigned short* av = (const unsigned short*)&sa[u];
      const unsigned short* bv = (const unsigned short*)&sb[u];
      unsigned int ov[4];
      for (int j = 0; j < 4; ++j) {
        float g0 = geluf(bf2f(av[2 * j])     + bf2f(bv[2 * j]));
        float g1 = geluf(bf2f(av[2 * j + 1]) + bf2f(bv[2 * j + 1]));
        ov[j] = pkbf(g0, g1);
      }
      *(int4*)&sH[r][seg * 32 + u * 8] = *(const int4*)ov;
    }
    float gp = 0.f;
    for (int u = 0; u < 4; ++u) {
      const unsigned short* av = (const unsigned short*)&ga[u];
      const unsigned short* bv = (const unsigned short*)&gb[u];
      float4 w0 = *(const float4*)(Wg2 + seg * 32 + u * 8);
      float4 w1 = *(const float4*)(Wg2 + seg * 32 + u * 8 + 4);
      gp += geluf(bf2f(av[0]) + bf2f(bv[0])) * w0.x;
      gp += geluf(bf2f(av[1]) + bf2f(bv[1])) * w0.y;
      gp += geluf(bf2f(av[2]) + bf2f(bv[2])) * w0.z;
      gp += geluf(bf2f(av[3]) + bf2f(bv[3])) * w0.w;
      gp += geluf(bf2f(av[4]) + bf2f(bv[4])) * w1.x;
      gp += geluf(bf2f(av[5]) + bf2f(bv[5])) * w1.y;
      gp += geluf(bf2f(av[6]) + bf2f(bv[6])) * w1.z;
      gp += geluf(bf2f(av[7]) + bf2f(bv[7])) * w1.w;
    }
    gp += __shfl_xor(gp, 1);
    gp += __shfl_xor(gp, 2);
    if (seg == 0) sGate[r] = sigmoidf_fast(gp + bg2[0]);
  }
  __syncthreads();  // B1: h1 + gate + dst staged

  int w = tid >> 6, lane = tid & 63, lr = lane & 15, q = lane >> 4;
  int c0 = 32 * w + lr, c1 = 32 * w + 16 + lr;
  const unsigned short* pB = wT + c0 * 128 + q * 8;

  bf16x8 B[2][4];
  floatx4 acc[4][2];
  auto zacc = [&]() {
    for (int mb = 0; mb < 4; ++mb)
      for (int nb = 0; nb < 2; ++nb) acc[mb][nb] = (floatx4){0.f, 0.f, 0.f, 0.f};
  };
  auto pass = [&](const unsigned short (*Ab)[136]) {
    for (int kb = 0; kb < 4; ++kb) {
      int k = kb * 32 + q * 8;
      for (int mb = 0; mb < 4; ++mb) {
        bf16x8 a = *(const bf16x8*)&Ab[16 * mb + lr][k];
        acc[mb][0] = __builtin_amdgcn_mfma_f32_16x16x32_bf16(a, B[0][kb], acc[mb][0], 0, 0, 0);
        acc[mb][1] = __builtin_amdgcn_mfma_f32_16x16x32_bf16(a, B[1][kb], acc[mb][1], 0, 0, 0);
      }
    }
  };

  // ---- stage 2: h2 = gelu(h1@W2 + b2), written back into sH in place ----
  LDB(pB + 4 * 16384, B);
  zacc();
  pass(sH);
  __syncthreads();  // B2: all h1 reads drained before overwrite
  {
    float bv0 = b2[c0], bv1 = b2[c1];
    for (int mb = 0; mb < 4; ++mb)
      for (int i = 0; i < 4; ++i) {
        int r = 16 * mb + 4 * q + i;
        unsigned int u = pkbf(geluf(acc[mb][0][i] + bv0), geluf(acc[mb][1][i] + bv1));
        sH[r][c0] = (unsigned short)u;
        sH[r][c1] = (unsigned short)(u >> 16);
      }
  }
  __syncthreads();  // B3: h2 tile visible

  // ---- stage 3 + LN partials ----
  LDB(pB + 5 * 16384, B);
  zacc();
  pass(sH);
  {
    float bv0 = b3[c0], bv1 = b3[c1];
    for (int mb = 0; mb < 4; ++mb)
      for (int i = 0; i < 4; ++i) {
        float x0 = acc[mb][0][i] + bv0;
        float x1 = acc[mb][1][i] + bv1;
        acc[mb][0][i] = x0; acc[mb][1][i] = x1;
        float s = x0 + x1, s2 = x0 * x0 + x1 * x1;
        s += __shfl_xor(s, 1); s += __shfl_xor(s, 2);
        s += __shfl_xor(s, 4); s += __shfl_xor(s, 8);
        s2 += __shfl_xor(s2, 1); s2 += __shfl_xor(s2, 2);
        s2 += __shfl_xor(s2, 4); s2 += __shfl_xor(s2, 8);
        if (lr == 0) { sR1[w][16 * mb + 4 * q + i] = s; sR2[w][16 * mb + 4 * q + i] = s2; }
      }
  }
  __syncthreads();  // B4
  if (tid < 64) {
    float s = sR1[0][tid] + sR1[1][tid] + sR1[2][tid] + sR1[3][tid];
    float s2 = sR2[0][tid] + sR2[1][tid] + sR2[2][tid] + sR2[3][tid];
    float m = s * (1.f / 128.f);
    float v = s2 * (1.f / 128.f) - m * m;
    sM[tid] = m;
    sRS[tid] = rsqrtf(v + LN_EPS);
  }
  __syncthreads();  // B5

  {
    float lg0 = ln_g[c0], lg1 = ln_g[c1];
    float lb0 = ln_b[c0], lb1 = ln_b[c1];
    for (int mb = 0; mb < 4; ++mb)
      for (int i = 0; i < 4; ++i) {
        int r = 16 * mb + 4 * q + i;
        int dst = sDst[r];
        float m = sM[r], rs = sRS[r], gt = sGate[r];
        float v0 = ((acc[mb][0][i] - m) * rs * lg0 + lb0) * gt;
        float v1 = ((acc[mb][1][i] - m) * rs * lg1 + lb1) * gt;
        float o0 = __shfl_xor(v0, 1);
        float o1 = __shfl_xor(v1, 1);
        if (dst >= 0) {
          unsigned int pk;
          int colb;
          if ((lr & 1) == 0) {
            pk = pkbf(v0, o0);
            colb = c0;
          } else {
            pk = pkbf(o1, v1);
            colb = c0 + 15;
          }
          unsigned short* addr = upd + (long long)dst * 128 + colb;
          asm volatile("global_atomic_pk_add_bf16 %0, %1, off"
                       :: "v"(addr), "v"(pk) : "memory");
        }
      }
  }
}

// ---------------------------------------------------------------------------
extern "C" void kernel_launch(void* const* d_in, const int* in_sizes, int n_in,
                              void* d_out, int out_size, void* d_ws, size_t ws_size,
                              hipStream_t stream) {
  const float* feat   = (const float*)d_in[0];
  const int* edge_src = (const int*)d_in[1];
  const int* edge_dst = (const int*)d_in[2];
  const float* W_src = (const float*)d_in[3];  const float* b_src = (const float*)d_in[4];
  const float* W_dst = (const float*)d_in[5];  const float* b_dst = (const float*)d_in[6];
  const float* W1a = (const float*)d_in[7];    const float* W1b = (const float*)d_in[8];
  const float* b1  = (const float*)d_in[9];
  const float* W2  = (const float*)d_in[10];   const float* b2  = (const float*)d_in[11];
  const float* W3  = (const float*)d_in[12];   const float* b3  = (const float*)d_in[13];
  const float* ln_g = (const float*)d_in[14];  const float* ln_b = (const float*)d_in[15];
  const float* Wg1a = (const float*)d_in[16];  const float* Wg1b = (const float*)d_in[17];
  const float* bg1  = (const float*)d_in[18];
  const float* Wg2  = (const float*)d_in[19];  const float* bg2 = (const float*)d_in[20];
  const float* W_out = (const float*)d_in[21]; const float* b_out = (const float*)d_in[22];

  int N = in_sizes[0] / 128;   // 100000
  int E = in_sizes[1];         // 400000

  // ws: [wT 288KB][SrcCat bf16 N*256][DstCat bf16 N*256][upd bf16 N*128]
  char* ws = (char*)d_ws;
  unsigned short* wT = (unsigned short*)ws;
  size_t off = 9 * 16384 * sizeof(unsigned short);
  unsigned short* SrcCat = (unsigned short*)(ws + off);
  off += (size_t)N * 256 * sizeof(unsigned short);
  unsigned short* DstCat = (unsigned short*)(ws + off);
  off += (size_t)N * 256 * sizeof(unsigned short);
  unsigned short* upd = (unsigned short*)(ws + off);

  prep_weights<<<36, 256, 0, stream>>>(W_src, W_dst, W1a, W1b, W2, W3, Wg1a, Wg1b,
                                       W_out, wT);
  int mtiles = (N + 63) / 64;
  node_fused<<<dim3(mtiles, 2), 256, 0, stream>>>(feat, wT, b_src, b_dst, b1, bg1,
                                                  SrcCat, DstCat, upd, N);
  edge_fused<<<(E + 63) / 64, 256, 0, stream>>>(SrcCat, DstCat, edge_src, edge_dst,
                                                wT, b2, b3, ln_g, ln_b, Wg2, bg2,
                                                upd, E);
  gemm_out<<<mtiles, 256, 0, stream>>>(upd, wT + 8 * 16384, b_out, (float*)d_out, N);
}

// Round 8
// 350.416 us; speedup vs baseline: 1.3232x; 1.0664x over previous
//
#include <hip/hip_runtime.h>
#include <hip/hip_bf16.h>
#include <math.h>

// MessagePassingLayer on MI355X — round 17.
// r16 established stable best: 373.7us (edge 158.5, non-edge ~215 vs ~50
// floor). node_fused is latency-bound at 16 waves/CU (50% occ). This round:
// node_fused goes 512 threads/block, 16 cols/wave (was 256/32): per-wave
// acc+B halve -> ~55-60 VGPR -> (512,8) = 4 blk x 8 waves = 32 waves/CU
// (100% occ). Tile stays 64x128, B-in-reg, A-from-LDS, LDS-staged coalesced
// epilogue — all the previously-regressing changes avoided. Single acc set
// live (A1 staged into dead sF right after its pass).
// edge_fused (r12 body) / gemm_out / prep unchanged.

typedef __bf16 bf16x8 __attribute__((ext_vector_type(8)));
typedef __bf16 bf16x2 __attribute__((ext_vector_type(2)));
typedef float floatx4 __attribute__((ext_vector_type(4)));

#define LN_EPS 1e-5f

__device__ __forceinline__ unsigned short f2bf(float x) {
  unsigned int u = __float_as_uint(x);
  u = u + 0x7fffu + ((u >> 16) & 1u);
  return (unsigned short)(u >> 16);
}

// packed pair -> one v_cvt_pk_bf16_f32 (RNE): lo in [15:0], hi in [31:16]
__device__ __forceinline__ unsigned int pkbf(float lo, float hi) {
  bf16x2 v;
  v.x = (__bf16)lo;
  v.y = (__bf16)hi;
  return __builtin_bit_cast(unsigned int, v);
}

__device__ __forceinline__ unsigned short f2bfh(float x) {
  __bf16 h = (__bf16)x;
  return __builtin_bit_cast(unsigned short, h);
}

__device__ __forceinline__ float bf2f(unsigned short s) {
  return __uint_as_float(((unsigned int)s) << 16);
}

__device__ __forceinline__ float geluf(float x) {
  float t = x * x;
  float u = x * (2.3022080f + 0.1029434f * t);
  float e = __builtin_amdgcn_exp2f(-u);
  return x * __builtin_amdgcn_rcpf(1.0f + e);
}

__device__ __forceinline__ float sigmoidf_fast(float x) {
  float e = __builtin_amdgcn_exp2f(-1.44269504f * x);
  return __builtin_amdgcn_rcpf(1.0f + e);
}

// ---------------------------------------------------------------------------
// prep: 9 [128,128] fp32 weights -> bf16 [n][k] (transposed). 36 blocks.
// slots: 0 WsrcT 1 WdstT 2 W1aT 3 W1bT 4 W2T 5 W3T 6 Wg1aT 7 Wg1bT 8 WoutT
// ---------------------------------------------------------------------------
__global__ __launch_bounds__(256) void prep_weights(
    const float* w0, const float* w1, const float* w2, const float* w3,
    const float* w4, const float* w5, const float* w6, const float* w7,
    const float* w8, unsigned short* out) {
  const float* srcs[9] = {w0, w1, w2, w3, w4, w5, w6, w7, w8};
  int m = blockIdx.x >> 2, c = blockIdx.x & 3;
  const float* src = srcs[m] + c * 32 * 128;
  __shared__ unsigned short sT[128][35];
  int tid = threadIdx.x;

  for (int it = 0; it < 4; ++it) {
    int f4 = tid + it * 256;
    float4 v = ((const float4*)src)[f4];
    int krel = f4 >> 5;
    int n0 = (f4 & 31) * 4;
    sT[n0 + 0][krel] = f2bf(v.x);
    sT[n0 + 1][krel] = f2bf(v.y);
    sT[n0 + 2][krel] = f2bf(v.z);
    sT[n0 + 3][krel] = f2bf(v.w);
  }
  __syncthreads();
  unsigned short* dst = out + m * 16384 + c * 32;
  for (int it = 0; it < 2; ++it) {
    int ch = tid + it * 256;
    int n = ch >> 2, kc = (ch & 3) * 8;
    unsigned short tmp[8];
    for (int j = 0; j < 8; ++j) tmp[j] = sT[n][kc + j];
    *(int4*)(dst + n * 128 + kc) = *(const int4*)tmp;
  }
}

#define LDB(pB, B)                                              \
  do {                                                          \
    const unsigned short* _p = (pB);                            \
    for (int kb = 0; kb < 4; ++kb) {                            \
      B[0][kb] = *(const bf16x8*)(_p + kb * 32);                \
      B[1][kb] = *(const bf16x8*)(_p + 2048 + kb * 32);         \
    }                                                           \
  } while (0)

// ---------------------------------------------------------------------------
// node_fused (512 thr, 8 waves, 16 cols/wave): blockIdx.y=0 -> SrcCat,
// y=1 -> DstCat. y==0 blocks zero their 64 rows of upd.
// Phases: feat->sF | B1 | h=sF@W+b -> sT | B2 | A1=sT@Wa+b -> sF (sF dead,
// col-private) | P=sT@Wg | B3 | P -> sT | B4 | coalesced copy out.
// One acc set live at a time; ~55-60 VGPR -> (512,8) = 32 waves/CU.
// ---------------------------------------------------------------------------
__global__ __launch_bounds__(512, 8) void node_fused(
    const float* __restrict__ feat, const unsigned short* __restrict__ wT,
    const float* __restrict__ b_src, const float* __restrict__ b_dst,
    const float* __restrict__ b1, const float* __restrict__ bg1,
    unsigned short* __restrict__ SrcCat, unsigned short* __restrict__ DstCat,
    unsigned short* __restrict__ upd, int M) {
  __shared__ __align__(16) unsigned short sF[64][136];
  __shared__ __align__(16) unsigned short sT[64][136];
  int tid = threadIdx.x;
  int r0 = blockIdx.x * 64;
  int y = blockIdx.y;

  if (y == 0) {  // zero upd rows [r0, r0+64): 1024 int4, 2 per thread
    int4 z = {0, 0, 0, 0};
    int4* p = (int4*)(upd + (long long)r0 * 128);
    for (int it = 0; it < 2; ++it) {
      int idx = tid + it * 512;
      if (r0 + (idx >> 4) < M) p[idx] = z;
    }
  }

  {  // stage feat -> sF: each thread 16 consecutive floats (64B) -> 2 int4
    int r = tid >> 3, seg = tid & 7;
    int row = r0 + r;
    const float* src = feat + (long long)row * 128 + seg * 16;
    if (row < M) {
      float4 f0 = *(const float4*)(src);
      float4 f1 = *(const float4*)(src + 4);
      float4 f2 = *(const float4*)(src + 8);
      float4 f3 = *(const float4*)(src + 12);
      unsigned int t0[4] = {pkbf(f0.x, f0.y), pkbf(f0.z, f0.w),
                            pkbf(f1.x, f1.y), pkbf(f1.z, f1.w)};
      unsigned int t1[4] = {pkbf(f2.x, f2.y), pkbf(f2.z, f2.w),
                            pkbf(f3.x, f3.y), pkbf(f3.z, f3.w)};
      *(int4*)&sF[r][seg * 16] = *(const int4*)t0;
      *(int4*)&sF[r][seg * 16 + 8] = *(const int4*)t1;
    } else {
      int4 z = {0, 0, 0, 0};
      *(int4*)&sF[r][seg * 16] = z;
      *(int4*)&sF[r][seg * 16 + 8] = z;
    }
  }
  __syncthreads();  // B1: feat staged

  int w = tid >> 6;                       // wave 0..7
  int lane = tid & 63, lr = lane & 15, q = lane >> 4;
  int c0 = 16 * w + lr;                   // this wave's 16 output cols
  const unsigned short* pB = wT + c0 * 128 + q * 8;

  const unsigned short* wH = pB + (y ? 1 : 0) * 16384;
  const unsigned short* wA = pB + (y ? 3 : 2) * 16384;
  const unsigned short* wG = pB + (y ? 7 : 6) * 16384;
  unsigned short* Cat = y ? DstCat : SrcCat;
  float hb = y ? b_dst[c0] : b_src[c0];
  float ab = y ? 0.f : b1[c0];
  float gb = y ? 0.f : bg1[c0];

  bf16x8 B[4];
  floatx4 acc[4];

  auto ldb = [&](const unsigned short* p) {
#pragma unroll
    for (int kb = 0; kb < 4; ++kb) B[kb] = *(const bf16x8*)(p + kb * 32);
  };
  auto zacc = [&]() {
#pragma unroll
    for (int mb = 0; mb < 4; ++mb) acc[mb] = (floatx4){0.f, 0.f, 0.f, 0.f};
  };
  auto pass = [&](const unsigned short (*Ab)[136]) {
#pragma unroll
    for (int kb = 0; kb < 4; ++kb) {
      int k = kb * 32 + q * 8;
#pragma unroll
      for (int mb = 0; mb < 4; ++mb) {
        bf16x8 a = *(const bf16x8*)&Ab[16 * mb + lr][k];
        acc[mb] = __builtin_amdgcn_mfma_f32_16x16x32_bf16(a, B[kb], acc[mb], 0, 0, 0);
      }
    }
  };
  auto stage = [&](unsigned short (*S)[136], float bv) {
#pragma unroll
    for (int mb = 0; mb < 4; ++mb)
#pragma unroll
      for (int i = 0; i < 4; ++i)
        S[16 * mb + 4 * q + i][c0] = f2bfh(acc[mb][i] + bv);
  };

  // h = feat@W{src,dst} + b -> sT
  ldb(wH); zacc(); pass(sF); stage(sT, hb);
  __syncthreads();  // B2: h visible; sF dead (all feat reads done)

  // A1 = h@W1 + b1 -> sF (col-private writes into dead buffer, no barrier)
  ldb(wA); zacc(); pass(sT); stage(sF, ab);
  // P = h@Wg1 + bg1
  ldb(wG); zacc(); pass(sT);
  __syncthreads();  // B3: all sT reads drained
  stage(sT, gb);    // P -> sT
  __syncthreads();  // B4: both staged tiles visible

  // coalesced copy: 64 rows x 256 cols bf16 = 2048 int4, 4 per thread
  for (int it = 0; it < 4; ++it) {
    int idx = tid + it * 512;
    int row = idx >> 5, c = idx & 31;   // c in [0,32): col chunk of 8
    if (r0 + row < M) {
      const void* src = (c < 16) ? (const void*)&sF[row][c * 8]
                                 : (const void*)&sT[row][(c - 16) * 8];
      *(int4*)(Cat + (long long)(r0 + row) * 256 + c * 8) = *(const int4*)src;
    }
  }
}

// ---------------------------------------------------------------------------
// out GEMM (r10 64-row version): d_out = upd(bf16)@Wout + b_out (fp32 out)
// ---------------------------------------------------------------------------
__global__ __launch_bounds__(256, 4) void gemm_out(
    const unsigned short* __restrict__ A, const unsigned short* __restrict__ Bt,
    const float* __restrict__ bias, float* __restrict__ C, int M) {
  __shared__ __align__(16) char smem[64 * 130 * 4];  // 33280 B
  unsigned short (*sA)[136] = (unsigned short(*)[136])smem;   // staging (17 KB)
  float (*sO)[130] = (float(*)[130])smem;                     // fp32 out tile
  int tid = threadIdx.x;
  int r0 = blockIdx.x * 64;

  {
    int r = tid >> 2, seg = tid & 3;
    int row = r0 + r;
    const int4* src = (const int4*)(A + (long long)row * 128);
    for (int it = 0; it < 4; ++it) {
      int c = seg * 4 + it;
      int4 v;
      if (row < M) v = src[c];
      else v = (int4){0, 0, 0, 0};
      *(int4*)&sA[r][c * 8] = v;
    }
  }
  __syncthreads();

  int w = tid >> 6, lane = tid & 63, lr = lane & 15, q = lane >> 4;
  int c0 = 32 * w + lr, c1 = 32 * w + 16 + lr;
  const unsigned short* pB = Bt + c0 * 128 + q * 8;

  bf16x8 B[2][4];
  LDB(pB, B);
  floatx4 acc[4][2];
  for (int mb = 0; mb < 4; ++mb)
    for (int nb = 0; nb < 2; ++nb) acc[mb][nb] = (floatx4){0.f, 0.f, 0.f, 0.f};
  for (int kb = 0; kb < 4; ++kb) {
    int k = kb * 32 + q * 8;
    for (int mb = 0; mb < 4; ++mb) {
      bf16x8 a = *(const bf16x8*)&sA[16 * mb + lr][k];
      acc[mb][0] = __builtin_amdgcn_mfma_f32_16x16x32_bf16(a, B[0][kb], acc[mb][0], 0, 0, 0);
      acc[mb][1] = __builtin_amdgcn_mfma_f32_16x16x32_bf16(a, B[1][kb], acc[mb][1], 0, 0, 0);
    }
  }
  __syncthreads();  // all sA reads done before fp32 overwrite

  float bv0 = bias[c0], bv1 = bias[c1];
  for (int mb = 0; mb < 4; ++mb)
    for (int i = 0; i < 4; ++i) {
      int r = 16 * mb + 4 * q + i;
      sO[r][c0] = acc[mb][0][i] + bv0;
      sO[r][c1] = acc[mb][1][i] + bv1;
    }
  __syncthreads();  // fp32 tile visible

  for (int it = 0; it < 8; ++it) {
    int idx = tid + it * 256;
    int row = idx >> 5, c = idx & 31;
    if (r0 + row < M)
      *(float4*)(C + (long long)(r0 + row) * 128 + c * 4) = *(const float4*)&sO[row][c * 4];
  }
}

// ---------------------------------------------------------------------------
// edge_fused: 64 edges/block, 256 thr (r12 body, unchanged; single dispatch).
// ---------------------------------------------------------------------------
__global__ __launch_bounds__(256, 6) void edge_fused(
    const unsigned short* __restrict__ SrcCat, const unsigned short* __restrict__ DstCat,
    const int* __restrict__ edge_src, const int* __restrict__ edge_dst,
    const unsigned short* __restrict__ wT,
    const float* __restrict__ b2, const float* __restrict__ b3,
    const float* __restrict__ ln_g, const float* __restrict__ ln_b,
    const float* __restrict__ Wg2, const float* __restrict__ bg2,
    unsigned short* __restrict__ upd, int E) {
  __shared__ __align__(16) unsigned short sH[64][136];  // h1 then h2 (in place)
  __shared__ int sDst[64];
  __shared__ float sGate[64];
  __shared__ float sR1[4][64];
  __shared__ float sR2[4][64];
  __shared__ float sM[64];
  __shared__ float sRS[64];
  // total: 17408 + 256 + 256 + 1024 + 1024 + 256 + 256 = 20480 B

  int tid = threadIdx.x;
  int e0 = blockIdx.x * 64;

  {  // gather + h1 + gate (partials reduced in-wave: seg quad = adjacent lanes)
    int r = tid >> 2, seg = tid & 3;
    int e = e0 + r;
    int ee = (e < E) ? e : (E - 1);
    int es = edge_src[ee], ed = edge_dst[ee];
    if (seg == 0) sDst[r] = (e < E) ? ed : -1;
    const unsigned short* ps = SrcCat + (long long)es * 256 + seg * 32;
    const unsigned short* pd = DstCat + (long long)ed * 256 + seg * 32;

    int4 sa[4], sb[4], ga[4], gb[4];
    for (int u = 0; u < 4; ++u) {
      sa[u] = ((const int4*)ps)[u];
      sb[u] = ((const int4*)pd)[u];
      ga[u] = ((const int4*)(ps + 128))[u];
      gb[u] = ((const int4*)(pd + 128))[u];
    }
    for (int u = 0; u < 4; ++u) {
      const unsigned short* av = (const unsigned short*)&sa[u];
      const unsigned short* bv = (const unsigned short*)&sb[u];
      unsigned int ov[4];
      for (int j = 0; j < 4; ++j) {
        float g0 = geluf(bf2f(av[2 * j])     + bf2f(bv[2 * j]));
        float g1 = geluf(bf2f(av[2 * j + 1]) + bf2f(bv[2 * j + 1]));
        ov[j] = pkbf(g0, g1);
      }
      *(int4*)&sH[r][seg * 32 + u * 8] = *(const int4*)ov;
    }
    float gp = 0.f;
    for (int u = 0; u < 4; ++u) {
      const unsigned short* av = (const unsigned short*)&ga[u];
      const unsigned short* bv = (const unsigned short*)&gb[u];
      float4 w0 = *(const float4*)(Wg2 + seg * 32 + u * 8);
      float4 w1 = *(const float4*)(Wg2 + seg * 32 + u * 8 + 4);
      gp += geluf(bf2f(av[0]) + bf2f(bv[0])) * w0.x;
      gp += geluf(bf2f(av[1]) + bf2f(bv[1])) * w0.y;
      gp += geluf(bf2f(av[2]) + bf2f(bv[2])) * w0.z;
      gp += geluf(bf2f(av[3]) + bf2f(bv[3])) * w0.w;
      gp += geluf(bf2f(av[4]) + bf2f(bv[4])) * w1.x;
      gp += geluf(bf2f(av[5]) + bf2f(bv[5])) * w1.y;
      gp += geluf(bf2f(av[6]) + bf2f(bv[6])) * w1.z;
      gp += geluf(bf2f(av[7]) + bf2f(bv[7])) * w1.w;
    }
    gp += __shfl_xor(gp, 1);
    gp += __shfl_xor(gp, 2);
    if (seg == 0) sGate[r] = sigmoidf_fast(gp + bg2[0]);
  }
  __syncthreads();  // B1: h1 + gate + dst staged

  int w = tid >> 6, lane = tid & 63, lr = lane & 15, q = lane >> 4;
  int c0 = 32 * w + lr, c1 = 32 * w + 16 + lr;
  const unsigned short* pB = wT + c0 * 128 + q * 8;

  bf16x8 B[2][4];
  floatx4 acc[4][2];
  auto zacc = [&]() {
    for (int mb = 0; mb < 4; ++mb)
      for (int nb = 0; nb < 2; ++nb) acc[mb][nb] = (floatx4){0.f, 0.f, 0.f, 0.f};
  };
  auto pass = [&](const unsigned short (*Ab)[136]) {
    for (int kb = 0; kb < 4; ++kb) {
      int k = kb * 32 + q * 8;
      for (int mb = 0; mb < 4; ++mb) {
        bf16x8 a = *(const bf16x8*)&Ab[16 * mb + lr][k];
        acc[mb][0] = __builtin_amdgcn_mfma_f32_16x16x32_bf16(a, B[0][kb], acc[mb][0], 0, 0, 0);
        acc[mb][1] = __builtin_amdgcn_mfma_f32_16x16x32_bf16(a, B[1][kb], acc[mb][1], 0, 0, 0);
      }
    }
  };

  // ---- stage 2: h2 = gelu(h1@W2 + b2), written back into sH in place ----
  LDB(pB + 4 * 16384, B);
  zacc();
  pass(sH);
  __syncthreads();  // B2: all h1 reads drained before overwrite
  {
    float bv0 = b2[c0], bv1 = b2[c1];
    for (int mb = 0; mb < 4; ++mb)
      for (int i = 0; i < 4; ++i) {
        int r = 16 * mb + 4 * q + i;
        unsigned int u = pkbf(geluf(acc[mb][0][i] + bv0), geluf(acc[mb][1][i] + bv1));
        sH[r][c0] = (unsigned short)u;
        sH[r][c1] = (unsigned short)(u >> 16);
      }
  }
  __syncthreads();  // B3: h2 tile visible

  // ---- stage 3 + LN partials ----
  LDB(pB + 5 * 16384, B);
  zacc();
  pass(sH);
  {
    float bv0 = b3[c0], bv1 = b3[c1];
    for (int mb = 0; mb < 4; ++mb)
      for (int i = 0; i < 4; ++i) {
        float x0 = acc[mb][0][i] + bv0;
        float x1 = acc[mb][1][i] + bv1;
        acc[mb][0][i] = x0; acc[mb][1][i] = x1;
        float s = x0 + x1, s2 = x0 * x0 + x1 * x1;
        s += __shfl_xor(s, 1); s += __shfl_xor(s, 2);
        s += __shfl_xor(s, 4); s += __shfl_xor(s, 8);
        s2 += __shfl_xor(s2, 1); s2 += __shfl_xor(s2, 2);
        s2 += __shfl_xor(s2, 4); s2 += __shfl_xor(s2, 8);
        if (lr == 0) { sR1[w][16 * mb + 4 * q + i] = s; sR2[w][16 * mb + 4 * q + i] = s2; }
      }
  }
  __syncthreads();  // B4
  if (tid < 64) {
    float s = sR1[0][tid] + sR1[1][tid] + sR1[2][tid] + sR1[3][tid];
    float s2 = sR2[0][tid] + sR2[1][tid] + sR2[2][tid] + sR2[3][tid];
    float m = s * (1.f / 128.f);
    float v = s2 * (1.f / 128.f) - m * m;
    sM[tid] = m;
    sRS[tid] = rsqrtf(v + LN_EPS);
  }
  __syncthreads();  // B5

  {
    float lg0 = ln_g[c0], lg1 = ln_g[c1];
    float lb0 = ln_b[c0], lb1 = ln_b[c1];
    for (int mb = 0; mb < 4; ++mb)
      for (int i = 0; i < 4; ++i) {
        int r = 16 * mb + 4 * q + i;
        int dst = sDst[r];
        float m = sM[r], rs = sRS[r], gt = sGate[r];
        float v0 = ((acc[mb][0][i] - m) * rs * lg0 + lb0) * gt;
        float v1 = ((acc[mb][1][i] - m) * rs * lg1 + lb1) * gt;
        float o0 = __shfl_xor(v0, 1);
        float o1 = __shfl_xor(v1, 1);
        if (dst >= 0) {
          unsigned int pk;
          int colb;
          if ((lr & 1) == 0) {
            pk = pkbf(v0, o0);
            colb = c0;
          } else {
            pk = pkbf(o1, v1);
            colb = c0 + 15;
          }
          unsigned short* addr = upd + (long long)dst * 128 + colb;
          asm volatile("global_atomic_pk_add_bf16 %0, %1, off"
                       :: "v"(addr), "v"(pk) : "memory");
        }
      }
  }
}

// ---------------------------------------------------------------------------
extern "C" void kernel_launch(void* const* d_in, const int* in_sizes, int n_in,
                              void* d_out, int out_size, void* d_ws, size_t ws_size,
                              hipStream_t stream) {
  const float* feat   = (const float*)d_in[0];
  const int* edge_src = (const int*)d_in[1];
  const int* edge_dst = (const int*)d_in[2];
  const float* W_src = (const float*)d_in[3];  const float* b_src = (const float*)d_in[4];
  const float* W_dst = (const float*)d_in[5];  const float* b_dst = (const float*)d_in[6];
  const float* W1a = (const float*)d_in[7];    const float* W1b = (const float*)d_in[8];
  const float* b1  = (const float*)d_in[9];
  const float* W2  = (const float*)d_in[10];   const float* b2  = (const float*)d_in[11];
  const float* W3  = (const float*)d_in[12];   const float* b3  = (const float*)d_in[13];
  const float* ln_g = (const float*)d_in[14];  const float* ln_b = (const float*)d_in[15];
  const float* Wg1a = (const float*)d_in[16];  const float* Wg1b = (const float*)d_in[17];
  const float* bg1  = (const float*)d_in[18];
  const float* Wg2  = (const float*)d_in[19];  const float* bg2 = (const float*)d_in[20];
  const float* W_out = (const float*)d_in[21]; const float* b_out = (const float*)d_in[22];

  int N = in_sizes[0] / 128;   // 100000
  int E = in_sizes[1];         // 400000

  // ws: [wT 288KB][SrcCat bf16 N*256][DstCat bf16 N*256][upd bf16 N*128]
  char* ws = (char*)d_ws;
  unsigned short* wT = (unsigned short*)ws;
  size_t off = 9 * 16384 * sizeof(unsigned short);
  unsigned short* SrcCat = (unsigned short*)(ws + off);
  off += (size_t)N * 256 * sizeof(unsigned short);
  unsigned short* DstCat = (unsigned short*)(ws + off);
  off += (size_t)N * 256 * sizeof(unsigned short);
  unsigned short* upd = (unsigned short*)(ws + off);

  prep_weights<<<36, 256, 0, stream>>>(W_src, W_dst, W1a, W1b, W2, W3, Wg1a, Wg1b,
                                       W_out, wT);
  int mtiles = (N + 63) / 64;
  node_fused<<<dim3(mtiles, 2), 512, 0, stream>>>(feat, wT, b_src, b_dst, b1, bg1,
                                                  SrcCat, DstCat, upd, N);
  edge_fused<<<(E + 63) / 64, 256, 0, stream>>>(SrcCat, DstCat, edge_src, edge_dst,
                                                wT, b2, b3, ln_g, ln_b, Wg2, bg2,
                                                upd, E);
  gemm_out<<<mtiles, 256, 0, stream>>>(upd, wT + 8 * 16384, b_out, (float*)d_out, N);
}